// Round 7
// baseline (445.724 us; speedup 1.0000x reference)
//
#include <hip/hip_runtime.h>
#include <math.h>

#define SUM_H 224
#define SUM_W 221
#define TROW  672   // floats per gene table row
#define NPT   8     // points per 16-lane group (pipelined)

// table layout (float offsets inside a gene row); all 16B-aligned
#define OBL0 0
#define OA0  128
#define OB0  256
#define OBL1 384
#define OA1  448
#define OB1  512
#define OBL2 576
#define OA2  608
#define OB2  640

// ---------------------------------------------------------------------------
// Kernel 1 (unchanged from R6, proven): per selected gene, bin edges bl
// (leading 0, last forced 1), A[k]=0.5*w[k]*exp(uh[k]), B[k]=0.5*w[k]*exp(uh[k+1]).
// Pad entries (index n-1 of A/B) are 0. One wave per gene.
// ---------------------------------------------------------------------------
__global__ __launch_bounds__(64) void gene_tables_kernel(
    const float* __restrict__ heights_weight,
    const float* __restrict__ widths_weight,
    const int*   __restrict__ genes_oi,
    float* __restrict__ tbl,
    int n_genes)
{
    int g = blockIdx.x;
    if (g >= n_genes) return;
    int gi = genes_oi[g];
    int l  = threadIdx.x;

    const float* wsrc = widths_weight  + (size_t)gi * SUM_W;
    const float* hsrc = heights_weight + (size_t)gi * SUM_H;
    float*       row  = tbl + (size_t)g * TROW;

    const int ns[3]   = {128, 64, 32};
    const int woff[3] = {0, 127, 190};
    const int hoff[3] = {0, 128, 192};
    const int obl[3]  = {OBL0, OBL1, OBL2};
    const int oa[3]   = {OA0, OA1, OA2};
    const int ob[3]   = {OB0, OB1, OB2};

    for (int lev = 0; lev < 3; lev++) {
        int m  = ns[lev] - 1;
        int j0 = 2 * l, j1 = 2 * l + 1;
        float u0 = (j0 < m) ? wsrc[woff[lev] + j0] : -1e30f;
        float u1 = (j1 < m) ? wsrc[woff[lev] + j1] : -1e30f;
        float mx = fmaxf(u0, u1);
        #pragma unroll
        for (int msk = 32; msk >= 1; msk >>= 1)
            mx = fmaxf(mx, __shfl_xor(mx, msk, 64));
        float e0 = (j0 < m) ? __expf(u0 - mx) : 0.f;
        float e1 = (j1 < m) ? __expf(u1 - mx) : 0.f;
        float local = e0 + e1;
        float incl  = local;
        #pragma unroll
        for (int off = 1; off < 64; off <<= 1) {
            float t = __shfl_up(incl, off, 64);
            if (l >= off) incl += t;
        }
        float total = __shfl(incl, 63, 64);
        float inv   = 1.0f / total;
        float w0    = e0 * inv;
        float w1    = e1 * inv;
        float excl  = incl - local;
        float c0 = (excl + e0) * inv;
        float c1 = (excl + e0 + e1) * inv;
        if (j0 <= m - 2) row[obl[lev] + j0 + 1] = c0;
        if (j1 <= m - 2) row[obl[lev] + j1 + 1] = c1;
        float h0 = (j0 < m) ? __expf(hsrc[hoff[lev] + j0])     : 0.f;
        float h1 = (j0 < m) ? __expf(hsrc[hoff[lev] + j0 + 1]) : 0.f;
        float h2 = (j1 < m) ? __expf(hsrc[hoff[lev] + j1 + 1]) : 0.f;
        if (j0 < m) { row[oa[lev] + j0] = 0.5f * w0 * h0;  row[ob[lev] + j0] = 0.5f * w0 * h1; }
        if (j1 < m) { row[oa[lev] + j1] = 0.5f * w1 * h1;  row[ob[lev] + j1] = 0.5f * w1 * h2; }
        if (l == 0) {
            row[obl[lev]]     = 0.0f;
            row[obl[lev] + m] = 1.0f;
            row[oa[lev]  + m] = 0.0f;
            row[ob[lev]  + m] = 0.0f;
        }
    }
}

// ---------------------------------------------------------------------------
// DPP 16-lane rotate-reductions (proven R3/R4/R6).
// ---------------------------------------------------------------------------
template<int CTRL>
__device__ __forceinline__ float dppf(float v) {
    return __builtin_bit_cast(float,
        __builtin_amdgcn_update_dpp(0, __builtin_bit_cast(int, v), CTRL, 0xF, 0xF, true));
}
template<int CTRL>
__device__ __forceinline__ int dppi(int v) {
    return __builtin_amdgcn_update_dpp(0, v, CTRL, 0xF, 0xF, true);
}
__device__ __forceinline__ float row16_sum(float v) {
    v += dppf<0x121>(v); v += dppf<0x122>(v); v += dppf<0x124>(v); v += dppf<0x128>(v);
    return v;
}
__device__ __forceinline__ int row16_sum_i(int v) {
    v += dppi<0x121>(v); v += dppi<0x122>(v); v += dppi<0x124>(v); v += dppi<0x128>(v);
    return v;
}

// ---------------------------------------------------------------------------
// Per-level state: 16 lanes per point; lane e owns contiguous elems [K*e, K*e+K).
// ---------------------------------------------------------------------------
template<int K>
struct Lvl {
    float bl[K];   // bin edges
    float a[K];    // staged A, then p = A*edh
    float b[K];    // staged B, then s = trapezoid mass
    float d[K];    // staged dh
    float bln;     // next lane's bl[0] (junk at e15, masked)
    float inva;    // 1/area (uniform)
};

template<int K>
__device__ __forceinline__ void lvl_load(const float* __restrict__ dh,
                                         const float* __restrict__ row,
                                         int obl, int oa, int ob,
                                         int e, Lvl<K>& L)
{
    const int j = K * e;
    if constexpr (K == 8) {
        *(float4*)&L.d[0]  = *(const float4*)(dh + j);
        *(float4*)&L.d[4]  = *(const float4*)(dh + j + 4);
        *(float4*)&L.bl[0] = *(const float4*)(row + obl + j);
        *(float4*)&L.bl[4] = *(const float4*)(row + obl + j + 4);
        *(float4*)&L.a[0]  = *(const float4*)(row + oa  + j);
        *(float4*)&L.a[4]  = *(const float4*)(row + oa  + j + 4);
        *(float4*)&L.b[0]  = *(const float4*)(row + ob  + j);
        *(float4*)&L.b[4]  = *(const float4*)(row + ob  + j + 4);
    } else if constexpr (K == 4) {
        *(float4*)&L.d[0]  = *(const float4*)(dh + j);
        *(float4*)&L.bl[0] = *(const float4*)(row + obl + j);
        *(float4*)&L.a[0]  = *(const float4*)(row + oa  + j);
        *(float4*)&L.b[0]  = *(const float4*)(row + ob  + j);
    } else {
        *(float2*)&L.d[0]  = *(const float2*)(dh + j);
        *(float2*)&L.bl[0] = *(const float2*)(row + obl + j);
        *(float2*)&L.a[0]  = *(const float2*)(row + oa  + j);
        *(float2*)&L.b[0]  = *(const float2*)(row + ob  + j);
    }
}

template<int K>
__device__ __forceinline__ void lvl_finish(int e, Lvl<K>& L)
{
    float ed[K];
    #pragma unroll
    for (int k = 0; k < K; k++) ed[k] = __expf(L.d[k]);
    float edn = __shfl_down(ed[0], 1, 16);     // junk at e15; A/B pad=0 => s=0 there
    L.bln     = __shfl_down(L.bl[0], 1, 16);   // junk at e15, masked in apply
    #pragma unroll
    for (int k = 0; k < K; k++) L.a[k] *= ed[k];                              // p
    #pragma unroll
    for (int k = 0; k < K - 1; k++) L.b[k] = fmaf(L.b[k], ed[k + 1], L.a[k]); // s
    L.b[K - 1] = fmaf(L.b[K - 1], edn, L.a[K - 1]);
    float lane = 0.f;
    #pragma unroll
    for (int k = 0; k < K; k++) lane += L.b[k];
    L.inva = __builtin_amdgcn_rcpf(row16_sum(lane));
}

template<int N, int K>
__device__ __forceinline__ void lvl_apply(int e, const Lvl<K>& L, float& x, float& prod)
{
    constexpr int LOGK = (K == 8) ? 3 : (K == 4) ? 2 : 1;
    bool c[K];
    #pragma unroll
    for (int k = 0; k < K; k++) c[k] = (x >= L.bl[k]);
    bool not15 = (e != 15);
    bool cn = not15 && (x >= L.bln);

    int   cnt  = 0;
    float part = 0.f;
    #pragma unroll
    for (int k = 0; k < K; k++) cnt += c[k] ? 1 : 0;
    #pragma unroll
    for (int k = 0; k < K - 1; k++) part += c[k + 1] ? L.b[k] : 0.f;
    part += cn ? L.b[K - 1] : 0.f;

    cnt  = row16_sum_i(cnt);
    part = row16_sum(part);

    int idx = cnt - 1;
    if (idx > N - 2) idx = N - 2;
    const int owner = idx >> LOGK;

    float sB = L.bl[0], sB1 = L.bl[1], sP = L.a[0], sS = L.b[0];
    #pragma unroll
    for (int jj = 1; jj < K; jj++) {
        bool  m   = (jj == K - 1) ? (c[jj] && not15) : c[jj];
        float nb1 = (jj == K - 1) ? L.bln : L.bl[jj + 1];
        sB  = m ? L.bl[jj] : sB;
        sB1 = m ? nb1      : sB1;
        sP  = m ? L.a[jj]  : sP;
        sS  = m ? L.b[jj]  : sS;
    }
    float sw = sB1 - sB;

    float inb = __shfl(sB, owner, 16);
    float ww  = __shfl(sw, owner, 16);
    float P   = __shfl(sP, owner, 16);
    float S   = __shfl(sS, owner, 16);

    float dEh   = fmaf(-2.f, P, S);            // 0.5*w*(Er-El)
    float rw    = __builtin_amdgcn_rcpf(ww);
    float alpha = (x - inb) * rw;
    float poly  = fmaf(fmaf(dEh, alpha, P + P), alpha, part);
    x = __builtin_amdgcn_fmed3f(poly * L.inva, 0.0f, 1.0f);
    prod *= fmaf(alpha, dEh, P) * (rw * L.inva);   // 0.5*t
}

// ---------------------------------------------------------------------------
// Kernel 2: pipelined — each 16-lane group processes NPT consecutive points.
// ---------------------------------------------------------------------------
struct PtState { Lvl<8> s0; Lvl<4> s1; Lvl<2> s2; };

__device__ __forceinline__ void issue_point(int pi, int g,
                                            const float* __restrict__ delta,
                                            const float* __restrict__ tbl,
                                            int e, PtState& S)
{
    const float* dh  = delta + (size_t)pi * SUM_H;
    const float* row = tbl   + (size_t)g  * TROW;
    lvl_load<8>(dh,       row, OBL0, OA0, OB0, e, S.s0);
    lvl_load<4>(dh + 128, row, OBL1, OA1, OB1, e, S.s1);
    lvl_load<2>(dh + 192, row, OBL2, OA2, OB2, e, S.s2);
}

__device__ __forceinline__ void process_point(int e, PtState& S, float x,
                                              float& xo, float& lado)
{
    lvl_finish<8>(e, S.s0);
    lvl_finish<4>(e, S.s1);
    lvl_finish<2>(e, S.s2);
    float prod = 1.f;
    lvl_apply<128, 8>(e, S.s0, x, prod);
    lvl_apply<64,  4>(e, S.s1, x, prod);
    lvl_apply<32,  2>(e, S.s2, x, prod);
    xo   = x;
    lado = __logf(prod) + 2.0794415416798357f;   // + ln(2^3)
}

__global__ __launch_bounds__(256, 3) void spline_kernel(
    const float* __restrict__ x_in,
    const float* __restrict__ delta,
    const int*   __restrict__ lgx,
    const float* __restrict__ tbl,
    float* __restrict__ out,
    float* __restrict__ lad_out,
    int n_points)
{
    const int tid  = threadIdx.x;
    const int e    = tid & 15;
    const int grp  = tid >> 4;                        // 0..15
    const int base = blockIdx.x * (16 * NPT) + grp * NPT;

    // per-point scalars: lane e (e<8) holds point base+e
    int pe = base + (e & 7);
    pe = (pe < n_points) ? pe : (n_points - 1);
    float xv = x_in[pe];
    int   gv = lgx[pe];

    auto pclamp = [&](int i) {
        int p = base + i;
        return (p < n_points) ? p : (n_points - 1);
    };

    PtState A, B;
    float xout = 0.f, ladout = 0.f;

    issue_point(pclamp(0), __shfl(gv, 0, 16), delta, tbl, e, A);

    #pragma unroll
    for (int i = 0; i < NPT; i += 2) {
        // issue i+1 into B, process i from A
        if (i + 1 < NPT)
            issue_point(pclamp(i + 1), __shfl(gv, i + 1, 16), delta, tbl, e, B);
        {
            float xo, lo;
            process_point(e, A, __shfl(xv, i, 16), xo, lo);
            if (e == i) { xout = xo; ladout = lo; }
        }
        // issue i+2 into A, process i+1 from B
        if (i + 2 < NPT)
            issue_point(pclamp(i + 2), __shfl(gv, i + 2, 16), delta, tbl, e, A);
        if (i + 1 < NPT) {
            float xo, lo;
            process_point(e, B, __shfl(xv, i + 1, 16), xo, lo);
            if (e == i + 1) { xout = xo; ladout = lo; }
        }
    }

    if (e < NPT) {
        int p = base + e;
        if (p < n_points) {
            out[p]     = xout;
            lad_out[p] = ladout;
        }
    }
}

extern "C" void kernel_launch(void* const* d_in, const int* in_sizes, int n_in,
                              void* d_out, int out_size, void* d_ws, size_t ws_size,
                              hipStream_t stream)
{
    const float* x        = (const float*)d_in[0];
    const float* delta    = (const float*)d_in[1];
    const float* hw       = (const float*)d_in[2];
    const float* ww       = (const float*)d_in[3];
    const int*   genes_oi = (const int*)  d_in[4];
    const int*   lgx      = (const int*)  d_in[5];

    int n_points   = in_sizes[0];
    int n_genes_oi = in_sizes[4];

    float* tbl = (float*)d_ws;

    hipLaunchKernelGGL(gene_tables_kernel, dim3(n_genes_oi), dim3(64), 0, stream,
                       hw, ww, genes_oi, tbl, n_genes_oi);

    const int ppb    = 16 * NPT;   // points per block
    const int blocks = (n_points + ppb - 1) / ppb;
    hipLaunchKernelGGL(spline_kernel, dim3(blocks), dim3(256), 0, stream,
                       x, delta, lgx, tbl,
                       (float*)d_out, (float*)d_out + n_points, n_points);
}

// Round 8
// 431.871 us; speedup vs baseline: 1.0321x; 1.0321x over previous
//
#include <hip/hip_runtime.h>
#include <math.h>

#define SUM_H 224
#define SUM_W 221

// slot-major gene table: tbl[slot * ng + g] = float4 {bl_k, A_k, B_k, 0}
//   A_k = 0.5*w_k*exp(uh[k]), B_k = 0.5*w_k*exp(uh[k+1])  (pads none; only m=n-1 slots)
// slot ranges: L0: 0..126, L1: 127..189, L2: 190..220  (221 slots total)

// ---------------------------------------------------------------------------
// Kernel 1: one wave per selected gene (softmax machinery proven R1-R6).
// ---------------------------------------------------------------------------
__global__ __launch_bounds__(64) void gene_tables_kernel(
    const float* __restrict__ heights_weight,
    const float* __restrict__ widths_weight,
    const int*   __restrict__ genes_oi,
    float4* __restrict__ tbl,
    int ng)
{
    int g = blockIdx.x;
    if (g >= ng) return;
    int gi = genes_oi[g];
    int l  = threadIdx.x;

    const float* wsrc = widths_weight  + (size_t)gi * SUM_W;
    const float* hsrc = heights_weight + (size_t)gi * SUM_H;

    const int ns[3]   = {128, 64, 32};
    const int woff[3] = {0, 127, 190};   // offsets into 221-wide width row
    const int hoff[3] = {0, 128, 192};   // offsets into 224-wide height row
    const int kb[3]   = {0, 127, 190};   // slot base per level

    for (int lev = 0; lev < 3; lev++) {
        int m  = ns[lev] - 1;
        int j0 = 2 * l, j1 = 2 * l + 1;   // lane l owns width elems 2l, 2l+1
        float u0 = (j0 < m) ? wsrc[woff[lev] + j0] : -1e30f;
        float u1 = (j1 < m) ? wsrc[woff[lev] + j1] : -1e30f;
        float mx = fmaxf(u0, u1);
        #pragma unroll
        for (int msk = 32; msk >= 1; msk >>= 1)
            mx = fmaxf(mx, __shfl_xor(mx, msk, 64));
        float e0 = (j0 < m) ? __expf(u0 - mx) : 0.f;
        float e1 = (j1 < m) ? __expf(u1 - mx) : 0.f;
        float local = e0 + e1;
        float incl  = local;
        #pragma unroll
        for (int off = 1; off < 64; off <<= 1) {
            float t = __shfl_up(incl, off, 64);
            if (l >= off) incl += t;
        }
        float total = __shfl(incl, 63, 64);
        float inv   = 1.0f / total;
        float excl  = incl - local;
        float edge0 = excl * inv;          // bl[j0]
        float edge1 = (excl + e0) * inv;   // bl[j1]
        float w0    = e0 * inv;
        float w1    = e1 * inv;
        // heights exp (uh[j+1] valid up to j=m-1: uh row has m+1 entries per level)
        float h0 = (j0 < m) ? __expf(hsrc[hoff[lev] + j0])     : 0.f;
        float h1 = (j0 < m) ? __expf(hsrc[hoff[lev] + j0 + 1]) : 0.f;
        float h2 = (j1 < m) ? __expf(hsrc[hoff[lev] + j1 + 1]) : 0.f;
        if (j0 < m) tbl[(size_t)(kb[lev] + j0) * ng + g] =
            make_float4(edge0, 0.5f * w0 * h0, 0.5f * w0 * h1, 0.f);
        if (j1 < m) tbl[(size_t)(kb[lev] + j1) * ng + g] =
            make_float4(edge1, 0.5f * w1 * h1, 0.5f * w1 * h2, 0.f);
    }
}

// ---------------------------------------------------------------------------
// Kernel 2: ONE LANE PER POINT. Serial walk over the level's m=N-1 slots with
// rolling register prefetch queues (delta: 8 float4-chunks ahead; table: one
// 4-slot bank ahead). No cross-lane ops, no LDS.
// ---------------------------------------------------------------------------
template<int N>
__device__ __forceinline__ void walk(const float* __restrict__ dhl,   // lane's delta row + level offset
                                     const float4* __restrict__ tp,  // slot 0 of level for this gene
                                     int ng, float& x, float& prod)
{
    constexpr int M  = N - 1;   // slots
    constexpr int NC = N / 4;   // delta float4 chunks (32/16/8, all >= 8)

    float4 q[8];
    #pragma unroll
    for (int i = 0; i < 8; i++) q[i] = *(const float4*)(dhl + 4 * i);
    float4 tq[2][4];
    #pragma unroll
    for (int t = 0; t < 4; t++) tq[0][t] = tp[(size_t)t * ng];

    float ed    = __expf(q[0].x);   // exp(dh[0])
    float area  = 0.f, part = 0.f, sprev = 0.f;
    float inb   = 0.f, b1 = 1.0f, Pk = 0.f, Sk = 0.f;

    #pragma unroll
    for (int ci = 0; ci < NC; ci++) {
        float4 cur = q[ci & 7];
        float dv[4];
        dv[0] = cur.y; dv[1] = cur.z; dv[2] = cur.w;
        dv[3] = (4 * ci + 4 <= M) ? q[(ci + 1) & 7].x : 0.f;   // d[4ci+4]
        if (ci + 8 < NC) q[ci & 7] = *(const float4*)(dhl + 4 * (ci + 8));
        #pragma unroll
        for (int t = 0; t < 4; t++) {
            int sl = 4 * (ci + 1) + t;
            if (sl < M) tq[(ci + 1) & 1][t] = tp[(size_t)sl * ng];
        }
        #pragma unroll
        for (int t = 0; t < 4; t++) {
            int j = 4 * ci + t;
            if (j < M) {
                float4 tt  = tq[ci & 1][t];
                float  ed1 = __expf(dv[t]);
                float  P   = tt.y * ed;               // 0.5*w*El
                float  s   = fmaf(tt.z, ed1, P);      // 0.5*w*(El+Er)
                area += s;
                bool   c   = (x >= tt.x);
                part += c ? sprev : 0.f;              // s_{j-1} counted iff x >= bl_j
                inb   = c ? tt.x : inb;
                Pk    = c ? P    : Pk;
                Sk    = c ? s    : Sk;
                b1    = c ? b1   : fminf(b1, tt.x);   // first false edge = right edge
                sprev = s;
                ed    = ed1;
            }
        }
    }
    float w     = b1 - inb;
    float rw    = __builtin_amdgcn_rcpf(w);
    float inva  = __builtin_amdgcn_rcpf(area);
    float dEh   = fmaf(-2.f, Pk, Sk);                 // 0.5*w*(Er-El)
    float alpha = (x - inb) * rw;
    float poly  = fmaf(fmaf(dEh, alpha, Pk + Pk), alpha, part);
    x = __builtin_amdgcn_fmed3f(poly * inva, 0.f, 1.f);
    prod *= fmaf(alpha, dEh, Pk) * (rw * inva);       // 0.5 * |det| factor
}

__global__ __launch_bounds__(256) void spline_kernel(
    const float* __restrict__ x_in,
    const float* __restrict__ delta,
    const int*   __restrict__ lgx,
    const float4* __restrict__ tbl,
    int ng,
    float* __restrict__ out,
    float* __restrict__ lad_out,
    int n_points)
{
    int p  = blockIdx.x * 256 + threadIdx.x;
    int pc = (p < n_points) ? p : (n_points - 1);

    float x = x_in[pc];
    int   g = lgx[pc];
    const float*  dh = delta + (size_t)pc * SUM_H;
    const float4* tg = tbl + g;

    float prod = 1.f;
    walk<128>(dh,       tg,                    ng, x, prod);
    walk<64> (dh + 128, tg + (size_t)127 * ng, ng, x, prod);
    walk<32> (dh + 192, tg + (size_t)190 * ng, ng, x, prod);

    if (p < n_points) {
        out[p]     = x;
        lad_out[p] = __logf(prod) + 2.0794415416798357f;   // + ln(2^3)
    }
}

extern "C" void kernel_launch(void* const* d_in, const int* in_sizes, int n_in,
                              void* d_out, int out_size, void* d_ws, size_t ws_size,
                              hipStream_t stream)
{
    const float* x        = (const float*)d_in[0];
    const float* delta    = (const float*)d_in[1];
    const float* hw       = (const float*)d_in[2];
    const float* ww       = (const float*)d_in[3];
    const int*   genes_oi = (const int*)  d_in[4];
    const int*   lgx      = (const int*)  d_in[5];

    int n_points   = in_sizes[0];
    int n_genes_oi = in_sizes[4];

    float4* tbl = (float4*)d_ws;

    hipLaunchKernelGGL(gene_tables_kernel, dim3(n_genes_oi), dim3(64), 0, stream,
                       hw, ww, genes_oi, tbl, n_genes_oi);

    const int blocks = (n_points + 255) / 256;
    hipLaunchKernelGGL(spline_kernel, dim3(blocks), dim3(256), 0, stream,
                       x, delta, lgx, tbl, n_genes_oi,
                       (float*)d_out, (float*)d_out + n_points, n_points);
}